// Round 8
// baseline (231.403 us; speedup 1.0000x reference)
//
#include <hip/hip_runtime.h>
#include <hip/hip_bf16.h>

// Problem: B=2,S=2048,D=1024,E=14,F=2048; N=4096 tokens.
// ws layout: ints [0..16) cnt, [16..32) cursor, [32..48) offs, [48) ntiles,
// [64..160) tiles, [160..4256) assign, [4256..8352) wgt, [8352..12576) list.
// hid bf16 @65536 (16.78MB); h16 bf16 @25165824... see offsets in launch.
// img (swizzled bf16 weight tile images) @25231360, 58.72MB, reused w1->w2.

#define NTOK 4096
#define NEXP 14
#define DDIM 1024
#define FDIM 2048

typedef __attribute__((ext_vector_type(8))) short short8;
typedef __attribute__((ext_vector_type(4))) float floatx4;

__device__ __forceinline__ unsigned bfr(float f) {  // f32 -> bf16 bits, RNE
  unsigned u = __float_as_uint(f);
  return (u + 0x7FFFu + ((u >> 16) & 1u)) >> 16;
}
__device__ __forceinline__ unsigned pk2(float a, float b) {
  return bfr(a) | (bfr(b) << 16);
}

__device__ __forceinline__ void gload16(const void* g, void* l) {
  __builtin_amdgcn_global_load_lds((const __attribute__((address_space(1))) void*)g,
                                   (__attribute__((address_space(3))) void*)l, 16, 0, 0);
}

__global__ void k_init(int* wsI, int* list) {
  int i = blockIdx.x * 256 + threadIdx.x;
  if (i < 160) wsI[i] = 0;
  if (i < 4224) list[i] = 0;
}

// one wave per token: fp64 logits -> argmax + softmax weight + expert count.
// router_w staged in LDS. Also emits h16 = bf16(h).
__global__ __launch_bounds__(256) void k_router(
    const float* __restrict__ x, const float* __restrict__ rw,
    int* __restrict__ assign, float* __restrict__ wgt,
    int* __restrict__ cnt, unsigned short* __restrict__ h16) {
  __shared__ float rwL[DDIM * NEXP];
  int tid = threadIdx.x;
  for (int i = tid; i < DDIM * NEXP / 4; i += 256)
    ((float4*)rwL)[i] = ((const float4*)rw)[i];
  __syncthreads();
  int wid = tid >> 6, lane = tid & 63;
  int n = blockIdx.x * 4 + wid;
  const float* xr = x + (size_t)n * DDIM;
  unsigned short* hr = h16 + (size_t)n * DDIM;
  double acc[NEXP];
#pragma unroll
  for (int e = 0; e < NEXP; e++) acc[e] = 0.0;
  for (int d = lane; d < DDIM; d += 64) {
    float xv = xr[d];
    hr[d] = (unsigned short)bfr(xv);
    const float* rp = rwL + d * NEXP;
#pragma unroll
    for (int e = 0; e < NEXP; e++) acc[e] += (double)xv * (double)rp[e];
  }
#pragma unroll
  for (int e = 0; e < NEXP; e++)
    for (int m = 32; m > 0; m >>= 1) acc[e] += __shfl_xor(acc[e], m, 64);
  if (lane == 0) {
    int best = 0; double bv = acc[0];
    for (int e = 1; e < NEXP; e++) if (acc[e] > bv) { bv = acc[e]; best = e; }
    double s = 0.0;
    for (int e = 0; e < NEXP; e++) s += exp(acc[e] - bv);
    assign[n] = best;
    wgt[n] = (float)(1.0 / s);
    atomicAdd(&cnt[best], 1);
  }
}

// one wave: shfl-scan prefix sums + parallel tile-descriptor build
__global__ void k_tiles(const int* __restrict__ cnt, int* __restrict__ offs,
                        int* __restrict__ tiles, int* __restrict__ ntl) {
  int l = threadIdx.x;
  int c = (l < NEXP) ? cnt[l] : 0;
  int nt = (c + 127) >> 7;
  int sc = c, st = nt;
  for (int m = 1; m < 64; m <<= 1) {
    int t1 = __shfl_up(sc, m, 64);
    int t2 = __shfl_up(st, m, 64);
    if (l >= m) { sc += t1; st += t2; }
  }
  if (l < NEXP) offs[l] = sc - c;
  if (l == NEXP - 1) offs[NEXP] = sc;
  int totT = __shfl(st, NEXP - 1, 64);
  if (l == 0) *ntl = totT;
  __shared__ int tstart[NEXP + 1];
  if (l < NEXP) tstart[l] = st - nt;
  if (l == NEXP - 1) tstart[NEXP] = st;
  __syncthreads();
  if (l < totT) {
    int e = 0;
    while (tstart[e + 1] <= l) e++;
    tiles[2 * l] = e;
    tiles[2 * l + 1] = (l - tstart[e]) * 128;
  }
}

__global__ void k_scatter(const int* __restrict__ assign, int* __restrict__ cursor,
                          const int* __restrict__ offs, int* __restrict__ list) {
  int n = blockIdx.x * 256 + threadIdx.x;
  if (n >= NTOK) return;
  int e = assign[n];
  int p = atomicAdd(&cursor[e], 1);
  list[offs[e] + p] = n;
}

// Weight-image pre-pass: one block per 64x64 tile of W[e][K][N] (f32).
// Emits the exact byte image of the GEMM's swizzled LDS B-tile:
//   chunk ci = col*8 + (k8 ^ (col&7)); chunk bytes = bf16 W[k8*8+j][col], j=0..7
// (16*ci == col*128 + (k8*16 ^ ((col&7)<<4)), the GEMM frag-read formula).
// LDS f32 transpose tile dword-swizzled: dw = k*64 + (n ^ (k&31))
// -> conflict-free stores, 2-way reads; image writes 1KB/wave coalesced.
__global__ __launch_bounds__(256) void k_prep(const float* __restrict__ W,
                                              unsigned short* __restrict__ img,
                                              int K, int N) {
  __shared__ float t32[4096];
  int b = blockIdx.x;
  int KB = K >> 6, NB = N >> 6;
  int kblk = b % KB, nb_ = b / KB;
  int nblk = nb_ % NB, e = nb_ / NB;
  const float* src = W + (size_t)e * K * N + (size_t)(kblk * 64) * N + nblk * 64;
  int t = threadIdx.x;
  int k = t >> 4, n4 = (t & 15) * 4;
#pragma unroll
  for (int j = 0; j < 4; j++) {
    int kk = k + j * 16;
    float4 v = *(const float4*)(src + (size_t)kk * N + n4);
    int sw = kk & 31;
    t32[kk * 64 + ((n4 + 0) ^ sw)] = v.x;
    t32[kk * 64 + ((n4 + 1) ^ sw)] = v.y;
    t32[kk * 64 + ((n4 + 2) ^ sw)] = v.z;
    t32[kk * 64 + ((n4 + 3) ^ sw)] = v.w;
  }
  __syncthreads();
  unsigned short* dst = img + (size_t)b * 4096;  // 8KB per tile image
#pragma unroll
  for (int c = 0; c < 2; c++) {
    int ci = t + c * 256;
    int col = ci >> 3, q = ci & 7, k8 = q ^ (col & 7);
    float f[8];
#pragma unroll
    for (int j = 0; j < 8; j++) {
      int kk = k8 * 8 + j;
      f[j] = t32[kk * 64 + (col ^ (kk & 31))];
    }
    uint4 o;
    o.x = pk2(f[0], f[1]);
    o.y = pk2(f[2], f[3]);
    o.z = pk2(f[4], f[5]);
    o.w = pk2(f[6], f[7]);
    *(uint4*)(dst + ci * 8) = o;
  }
}

// Image GEMM: tile 128x64, BK=64, 4 waves (2x2, each 64x32).
// BOTH operands via global_load_lds (A: gathered bf16 rows, pre-swizzled source;
// B: linear copy of the pre-swizzled weight image). Double-buffered LDS,
// 2 raw barriers/iter, counted s_waitcnt vmcnt(6) (T4 — never drains in loop).
// LAYER 1: A=h16, B=img(w1), exact-GELU -> hid (bf16)
// LAYER 2: A=hid, B=img(w2), (+b2)*wgt  -> out (f32)
template <int LAYER>
__global__ __launch_bounds__(256, 3) void k_gemm_img(
    const unsigned short* __restrict__ Xb, const unsigned short* __restrict__ img,
    const float* __restrict__ Bias, const float* __restrict__ wgt,
    unsigned short* __restrict__ outB, float* __restrict__ outF,
    const int* __restrict__ wsI) {
  constexpr int K = (LAYER == 1) ? DDIM : FDIM;
  constexpr int N = (LAYER == 1) ? FDIM : DDIM;
  constexpr int NIT = K / 64;
  constexpr int KB = K / 64, NB = N / 64;

  const int* cnt = wsI;
  const int* offs = wsI + 32;
  const int* ntl = wsI + 48;
  const int* tiles = wsI + 64;
  const int* list = wsI + 8352;

  int tI = blockIdx.y;
  if (tI >= *ntl) return;
  int e = tiles[2 * tI], m0 = tiles[2 * tI + 1];
  int rows = cnt[e] - m0;
  int base = offs[e] + m0;
  int n0 = blockIdx.x * 64;

  __shared__ char sA[2][16384];  // bf16 [128][64], XOR-swizzled via source
  __shared__ char sB[2][8192];   // bf16 [64][64], image bytes == swizzled layout
  __shared__ int tokL[128];
  __shared__ float wgtL[128];

  int tid = threadIdx.x;
  if (tid < 128) {
    int tok = list[base + tid];  // pad slots zero-init -> token 0 (valid data)
    tokL[tid] = tok;
    if (LAYER == 2) wgtL[tid] = wgt[tok];
  }
  __syncthreads();

  int lane = tid & 63, wid = tid >> 6, wm = wid >> 1, wn = wid & 1;

  // A source: per-lane pre-swizzled; dest = wave-uniform chunk base (+lane*16 HW)
  const char* gA[4];
  {
    unsigned sw = (unsigned)(((lane & 7) * 16) ^ ((lane >> 3) << 4));
#pragma unroll
    for (int j = 0; j < 4; j++) {
      int row = wid * 32 + j * 8 + (lane >> 3);
      gA[j] = (const char*)(Xb + (size_t)tokL[row] * K) + sw;
    }
  }
  // B source: linear per-lane walk through this (e, n-block)'s image tiles
  const char* gB = (const char*)img +
                   (size_t)((e * NB + (n0 >> 6)) * KB) * 8192 + wid * 2048 + lane * 16;

  floatx4 acc[4][2];
#pragma unroll
  for (int i = 0; i < 4; i++)
#pragma unroll
    for (int j = 0; j < 2; j++) acc[i][j] = (floatx4){0.f, 0.f, 0.f, 0.f};

#define GLOAD_AB(it, p)                                                     \
  do {                                                                      \
    _Pragma("unroll") for (int j = 0; j < 4; j++)                           \
        gload16(gA[j] + (size_t)(it) * 128, sA[p] + (wid * 4 + j) * 1024);  \
    _Pragma("unroll") for (int j = 0; j < 2; j++)                           \
        gload16(gB + (size_t)(it) * 8192 + j * 1024,                        \
                sB[p] + wid * 2048 + j * 1024);                             \
  } while (0)

#define MFMA_PHASE(P)                                                                    \
  do {                                                                                   \
    const char* A_ = sA[P];                                                              \
    const char* B_ = sB[P];                                                              \
    _Pragma("unroll") for (int kc = 0; kc < 2; kc++) {                                   \
      short8 af[4], bf[2];                                                               \
      int kb = kc * 64 + ((lane >> 4) << 4);                                             \
      _Pragma("unroll") for (int f = 0; f < 4; f++) {                                    \
        int rr = wm * 64 + f * 16 + (lane & 15);                                         \
        af[f] = *(const short8*)(A_ + rr * 128 + (kb ^ ((rr & 7) << 4)));                \
      }                                                                                  \
      _Pragma("unroll") for (int f = 0; f < 2; f++) {                                    \
        int cc = wn * 32 + f * 16 + (lane & 15);                                         \
        bf[f] = *(const short8*)(B_ + cc * 128 + (kb ^ ((cc & 7) << 4)));                \
      }                                                                                  \
      _Pragma("unroll") for (int fm = 0; fm < 4; fm++)                                   \
      _Pragma("unroll") for (int fn = 0; fn < 2; fn++)                                   \
          acc[fm][fn] =                                                                  \
              __builtin_amdgcn_mfma_f32_16x16x32_bf16(af[fm], bf[fn], acc[fm][fn], 0, 0, 0); \
    }                                                                                    \
  } while (0)

  GLOAD_AB(0, 0);
  for (int it = 0; it < NIT - 1; ++it) {
    int p = it & 1;
    __builtin_amdgcn_sched_barrier(0);
    __builtin_amdgcn_s_barrier();  // all reads of buf p^1 (iter it-1) done
    GLOAD_AB(it + 1, p ^ 1);
    __builtin_amdgcn_sched_barrier(0);
    asm volatile("s_waitcnt vmcnt(6)" ::: "memory");  // iter-it loads landed
    __builtin_amdgcn_s_barrier();
    __builtin_amdgcn_sched_barrier(0);
    MFMA_PHASE(p);
  }
  {
    int p = (NIT - 1) & 1;
    __builtin_amdgcn_sched_barrier(0);
    __builtin_amdgcn_s_barrier();
    asm volatile("s_waitcnt vmcnt(0)" ::: "memory");
    __builtin_amdgcn_s_barrier();
    __builtin_amdgcn_sched_barrier(0);
    MFMA_PHASE(p);
  }
#undef GLOAD_AB
#undef MFMA_PHASE

  // epilogue. C frag mapping: col = lane&15, row = (lane>>4)*4 + r
  float bv[2];
#pragma unroll
  for (int f = 0; f < 2; f++) bv[f] = Bias[(size_t)e * N + n0 + wn * 32 + f * 16 + (lane & 15)];
#pragma unroll
  for (int fm = 0; fm < 4; fm++) {
#pragma unroll
    for (int r = 0; r < 4; r++) {
      int gr = wm * 64 + fm * 16 + ((lane >> 4) << 2) + r;
      if (gr < rows) {
        int tok = tokL[gr];
#pragma unroll
        for (int fn = 0; fn < 2; fn++) {
          int col = n0 + wn * 32 + fn * 16 + (lane & 15);
          float v = acc[fm][fn][r] + bv[fn];
          if (LAYER == 1) {
            v = 0.5f * v * (1.0f + erff(v * 0.70710678118654752f));  // exact GELU
            outB[(size_t)tok * FDIM + col] = (unsigned short)bfr(v);
          } else {
            outF[(size_t)tok * DDIM + col] = v * wgtL[gr];
          }
        }
      }
    }
  }
}

// ---- Fallback (R7 kernel, used if ws_size too small for weight images) ----
template <int LAYER>
__global__ __launch_bounds__(256, 3) void k_gemm_rs(
    const unsigned short* __restrict__ Xb, const float* __restrict__ W,
    const float* __restrict__ Bias, const float* __restrict__ wgt,
    unsigned short* __restrict__ outB, float* __restrict__ outF,
    const int* __restrict__ wsI) {
  constexpr int K = (LAYER == 1) ? DDIM : FDIM;
  constexpr int N = (LAYER == 1) ? FDIM : DDIM;
  constexpr int NIT = K / 64;
  const int* cnt = wsI;
  const int* offs = wsI + 32;
  const int* ntl = wsI + 48;
  const int* tiles = wsI + 64;
  const int* list = wsI + 8352;
  int tI = blockIdx.y;
  if (tI >= *ntl) return;
  int e = tiles[2 * tI], m0 = tiles[2 * tI + 1];
  int rows = cnt[e] - m0;
  int base = offs[e] + m0;
  int n0 = blockIdx.x * 64;
  __shared__ char sA[2][16384];
  __shared__ char sB[2][8192];
  __shared__ int tokL[128];
  __shared__ float wgtL[128];
  int tid = threadIdx.x;
  if (tid < 128) {
    int tok = list[base + tid];
    tokL[tid] = tok;
    if (LAYER == 2) wgtL[tid] = wgt[tok];
  }
  __syncthreads();
  int lane = tid & 63, wid = tid >> 6, wm = wid >> 1, wn = wid & 1;
  const char* gA[4];
  {
    unsigned sw = (unsigned)(((lane & 7) * 16) ^ ((lane >> 3) << 4));
#pragma unroll
    for (int j = 0; j < 4; j++) {
      int row = wid * 32 + j * 8 + (lane >> 3);
      gA[j] = (const char*)(Xb + (size_t)tokL[row] * K) + sw;
    }
  }
  int nn = tid & 63;
  int krow0 = (tid >> 6) * 4;
  const float* Wrow0 = W + (size_t)e * K * N + (size_t)krow0 * N + n0 + nn;
  const float* Wrow1 = Wrow0 + (size_t)64 * N;
  floatx4 acc[4][2];
#pragma unroll
  for (int i = 0; i < 4; i++)
#pragma unroll
    for (int j = 0; j < 2; j++) acc[i][j] = (floatx4){0.f, 0.f, 0.f, 0.f};
  float rB0[4][4], rB1[4][4];
#define ISSUE_B(PW)                                          \
  do {                                                       \
    _Pragma("unroll") for (int j = 0; j < 4; j++)            \
    _Pragma("unroll") for (int r = 0; r < 4; r++)            \
        rB##PW[j][r] = Wrow##PW[(size_t)(j * 16 + r) * N];   \
    Wrow##PW += (size_t)128 * N;                             \
  } while (0)
#define WRITE_B(PW)                                                                  \
  _Pragma("unroll") for (int j = 0; j < 4; j++) {                                    \
    uint2 wv;                                                                        \
    wv.x = pk2(rB##PW[j][0], rB##PW[j][1]);                                          \
    wv.y = pk2(rB##PW[j][2], rB##PW[j][3]);                                          \
    *(uint2*)(sB[PW] + nn * 128 + (((krow0 + j * 16) * 2) ^ ((nn & 7) << 4))) = wv;  \
  }
#define GLOADA(k0, p)                                        \
  _Pragma("unroll") for (int j = 0; j < 4; j++)              \
      gload16(gA[j] + (size_t)(k0) * 2, sA[p] + (wid * 4 + j) * 1024);
#define MFMA_PHASE(P)                                                                    \
  do {                                                                                   \
    const char* A_ = sA[P];                                                              \
    const char* B_ = sB[P];                                                              \
    _Pragma("unroll") for (int kc = 0; kc < 2; kc++) {                                   \
      short8 af[4], bf[2];                                                               \
      int kb = kc * 64 + ((lane >> 4) << 4);                                             \
      _Pragma("unroll") for (int f = 0; f < 4; f++) {                                    \
        int rr = wm * 64 + f * 16 + (lane & 15);                                         \
        af[f] = *(const short8*)(A_ + rr * 128 + (kb ^ ((rr & 7) << 4)));                \
      }                                                                                  \
      _Pragma("unroll") for (int f = 0; f < 2; f++) {                                    \
        int cc = wn * 32 + f * 16 + (lane & 15);                                         \
        bf[f] = *(const short8*)(B_ + cc * 128 + (kb ^ ((cc & 7) << 4)));                \
      }                                                                                  \
      _Pragma("unroll") for (int fm = 0; fm < 4; fm++)                                   \
      _Pragma("unroll") for (int fn = 0; fn < 2; fn++)                                   \
          acc[fm][fn] =                                                                  \
              __builtin_amdgcn_mfma_f32_16x16x32_bf16(af[fm], bf[fn], acc[fm][fn], 0, 0, 0); \
    }                                                                                    \
  } while (0)
#define STEP(P, DO1, DO2, K1, VM)                                     \
  do {                                                                \
    __builtin_amdgcn_s_barrier();                                     \
    WRITE_B(P);                                                       \
    __builtin_amdgcn_sched_barrier(0);                                \
    if (DO1) { GLOADA((K1), P ^ 1); }                                 \
    if (DO2) { ISSUE_B(P); }                                          \
    __builtin_amdgcn_sched_barrier(0);                                \
    asm volatile("s_waitcnt vmcnt(" #VM ") lgkmcnt(0)" ::: "memory"); \
    __builtin_amdgcn_sched_barrier(0);                                \
    __builtin_amdgcn_s_barrier();                                     \
    MFMA_PHASE(P);                                                    \
  } while (0)
  ISSUE_B(0);
  GLOADA(0, 0);
  ISSUE_B(1);
  for (int it = 0; it < NIT - 2; it += 2) {
    STEP(0, 1, 1, (it + 1) * 64, 36);
    STEP(1, 1, 1, (it + 2) * 64, 36);
  }
  STEP(0, 1, 0, (NIT - 1) * 64, 20);
  STEP(1, 0, 0, 0, 0);
#undef ISSUE_B
#undef WRITE_B
#undef GLOADA
#undef MFMA_PHASE
#undef STEP
  float bv[2];
#pragma unroll
  for (int f = 0; f < 2; f++) bv[f] = Bias[(size_t)e * N + n0 + wn * 32 + f * 16 + (lane & 15)];
#pragma unroll
  for (int fm = 0; fm < 4; fm++) {
#pragma unroll
    for (int r = 0; r < 4; r++) {
      int gr = wm * 64 + fm * 16 + ((lane >> 4) << 2) + r;
      if (gr < rows) {
        int tok = tokL[gr];
#pragma unroll
        for (int fn = 0; fn < 2; fn++) {
          int col = n0 + wn * 32 + fn * 16 + (lane & 15);
          float v = acc[fm][fn][r] + bv[fn];
          if (LAYER == 1) {
            v = 0.5f * v * (1.0f + erff(v * 0.70710678118654752f));
            outB[(size_t)tok * FDIM + col] = (unsigned short)bfr(v);
          } else {
            outF[(size_t)tok * DDIM + col] = v * wgtL[gr];
          }
        }
      }
    }
  }
}

extern "C" void kernel_launch(void* const* d_in, const int* in_sizes, int n_in,
                              void* d_out, int out_size, void* d_ws, size_t ws_size,
                              hipStream_t stream) {
  const float* h  = (const float*)d_in[0];
  const float* rw = (const float*)d_in[1];
  const float* w1 = (const float*)d_in[2];
  const float* b1 = (const float*)d_in[3];
  const float* w2 = (const float*)d_in[4];
  const float* b2 = (const float*)d_in[5];
  float* out = (float*)d_out;

  int* wsI = (int*)d_ws;
  int* assign = wsI + 160;
  float* wgt = (float*)(wsI + 4256);
  int* list = wsI + 8352;
  unsigned short* hid = (unsigned short*)((char*)d_ws + 65536);
  unsigned short* h16 = (unsigned short*)((char*)d_ws + 65536 + 16777216);
  unsigned short* img = (unsigned short*)((char*)d_ws + 65536 + 16777216 + 8388608);

  k_init<<<17, 256, 0, stream>>>(wsI, list);
  k_router<<<NTOK / 4, 256, 0, stream>>>(h, rw, assign, wgt, wsI, h16);
  k_tiles<<<1, 64, 0, stream>>>(wsI, wsI + 32, wsI + 64, wsI + 48);
  k_scatter<<<NTOK / 256, 256, 0, stream>>>(assign, wsI + 16, wsI + 32, list);

  if (ws_size >= (size_t)65536 + 16777216 + 8388608 + 58720256) {
    // image path: prep(w1) -> L1 -> prep(w2) -> L2 (stream-serial, img reused)
    k_prep<<<NEXP * (FDIM / 64) * (DDIM / 64), 256, 0, stream>>>(w1, img, DDIM, FDIM);
    k_gemm_img<1><<<dim3(FDIM / 64, 45), 256, 0, stream>>>(h16, img, b1, nullptr, hid, nullptr, wsI);
    k_prep<<<NEXP * (DDIM / 64) * (FDIM / 64), 256, 0, stream>>>(w2, img, FDIM, DDIM);
    k_gemm_img<2><<<dim3(DDIM / 64, 45), 256, 0, stream>>>(hid, img, b2, wgt, nullptr, out, wsI);
  } else {
    k_gemm_rs<1><<<dim3(FDIM / 64, 45), 256, 0, stream>>>(h16, w1, b1, nullptr, hid, nullptr, wsI);
    k_gemm_rs<2><<<dim3(DDIM / 64, 45), 256, 0, stream>>>(hid, w2, b2, wgt, nullptr, out, wsI);
  }
}

// Round 9
// 222.009 us; speedup vs baseline: 1.0423x; 1.0423x over previous
//
#include <hip/hip_runtime.h>
#include <hip/hip_bf16.h>

// Problem: B=2,S=2048,D=1024,E=14,F=2048; N=4096 tokens.
// ws layout (bytes):
//   [0)      ints: cnt[0..14) @0, ntl @ int48, tiles @ int64..160, wgt(f32) @ int4256
//   [65536)  list: 14 regions x 4096 ints (224KB)
//   [294912) rwT: transposed router_w (14x1024 f32, 57KB)
//   [393216) hid bf16 (16.78MB)
//   [17170432) h16 bf16 (8.39MB)   -- dead after gemm1; img2 overlays it
//   [25559040) img1 (29.36MB)      -- swizzled bf16 w1 tile images
//   img2 @17170432 (29.36MB)       -- written by prep2 after gemm1
// total need: 54919168 bytes (R8 proved ws_size >= 83.9MB)

#define NTOK 4096
#define NEXP 14
#define DDIM 1024
#define FDIM 2048

typedef __attribute__((ext_vector_type(8))) short short8;
typedef __attribute__((ext_vector_type(4))) float floatx4;

__device__ __forceinline__ unsigned bfr(float f) {  // f32 -> bf16 bits, RNE
  unsigned u = __float_as_uint(f);
  return (u + 0x7FFFu + ((u >> 16) & 1u)) >> 16;
}
__device__ __forceinline__ unsigned pk2(float a, float b) {
  return bfr(a) | (bfr(b) << 16);
}

__device__ __forceinline__ void gload16(const void* g, void* l) {
  __builtin_amdgcn_global_load_lds((const __attribute__((address_space(1))) void*)g,
                                   (__attribute__((address_space(3))) void*)l, 16, 0, 0);
}

// zero cnt + build transposed router weights rwT[e][d]
__global__ void k_init(const float* __restrict__ rw, float* __restrict__ rwT,
                       int* __restrict__ cnt) {
  int i = blockIdx.x * 256 + threadIdx.x;
  if (i < 16) cnt[i] = 0;
  if (i < DDIM * NEXP) rwT[(i % NEXP) * DDIM + i / NEXP] = rw[i];
}

// one wave per token, NO LDS: fp64 logits from coalesced float4 reads of x/rwT,
// butterfly allreduce, all-lane fp32 softmax tail, fused scatter into list.
// Also emits h16 = bf16(h).
__global__ __launch_bounds__(256) void k_router(
    const float* __restrict__ x, const float* __restrict__ rwT,
    float* __restrict__ wgt, int* __restrict__ cnt, int* __restrict__ list,
    unsigned short* __restrict__ h16) {
  int wid = threadIdx.x >> 6, lane = threadIdx.x & 63;
  int n = blockIdx.x * 4 + wid;
  const float* xr = x + (size_t)n * DDIM;
  unsigned short* hr = h16 + (size_t)n * DDIM;
  double acc[NEXP];
#pragma unroll
  for (int e = 0; e < NEXP; e++) acc[e] = 0.0;
#pragma unroll
  for (int i = 0; i < 4; i++) {
    int d0 = i * 256 + lane * 4;
    float4 xv = *(const float4*)(xr + d0);
    uint2 hb;
    hb.x = pk2(xv.x, xv.y);
    hb.y = pk2(xv.z, xv.w);
    *(uint2*)(hr + d0) = hb;
    double x0 = xv.x, x1 = xv.y, x2 = xv.z, x3 = xv.w;
#pragma unroll
    for (int e = 0; e < NEXP; e++) {
      float4 rv = *(const float4*)(rwT + e * DDIM + d0);
      acc[e] += x0 * (double)rv.x + x1 * (double)rv.y + x2 * (double)rv.z + x3 * (double)rv.w;
    }
  }
#pragma unroll
  for (int e = 0; e < NEXP; e++)
    for (int m = 32; m > 0; m >>= 1) acc[e] += __shfl_xor(acc[e], m, 64);
  // every lane now holds all 14 logits
  int best = 0;
  double bv = acc[0];
#pragma unroll
  for (int e = 1; e < NEXP; e++)
    if (acc[e] > bv) { bv = acc[e]; best = e; }
  float s = 0.f;
#pragma unroll
  for (int e = 0; e < NEXP; e++) s += expf((float)(acc[e] - bv));
  if (lane == 0) {
    wgt[n] = 1.0f / s;
    int p = atomicAdd(&cnt[best], 1);
    list[best * NTOK + p] = n;
  }
}

// one wave: tile-count scan + parallel tile-descriptor build
__global__ void k_tiles(const int* __restrict__ cnt, int* __restrict__ tiles,
                        int* __restrict__ ntl) {
  int l = threadIdx.x;
  int c = (l < NEXP) ? cnt[l] : 0;
  int nt = (c + 127) >> 7;
  int st = nt;
  for (int m = 1; m < 64; m <<= 1) {
    int t = __shfl_up(st, m, 64);
    if (l >= m) st += t;
  }
  __shared__ int tstart[NEXP + 1];
  if (l < NEXP) tstart[l] = st - nt;
  if (l == NEXP - 1) { tstart[NEXP] = st; *ntl = st; }
  __syncthreads();
  int totT = tstart[NEXP];
  if (l < totT) {
    int e = 0;
    while (tstart[e + 1] <= l) e++;
    tiles[2 * l] = e;
    tiles[2 * l + 1] = (l - tstart[e]) * 128;
  }
}

// Weight-image pre-pass, 4 k-tiles per block (z-loop).
// Emits the exact byte image of the GEMM's swizzled LDS B-tile:
//   chunk ci = col*8 + (k8 ^ (col&7)); bytes = bf16 W[k8*8+j][col], j=0..7.
// LDS f32 transpose tile dword-swizzled: dw = k*64 + (n ^ (k&31)).
__global__ __launch_bounds__(256) void k_prep(const float* __restrict__ W,
                                              unsigned short* __restrict__ img,
                                              int K, int N) {
  __shared__ float t32[4096];
  int KB = K >> 6, NB = N >> 6, K4 = KB >> 2;
  int b = blockIdx.x;
  int kb4 = b % K4;
  int nb_ = b / K4;
  int nblk = nb_ % NB, e = nb_ / NB;
  int t = threadIdx.x;
  int k = t >> 4, n4 = (t & 15) * 4;
  for (int z = 0; z < 4; z++) {
    int kblk = kb4 * 4 + z;
    const float* src = W + (size_t)e * K * N + (size_t)(kblk * 64) * N + nblk * 64;
#pragma unroll
    for (int j = 0; j < 4; j++) {
      int kk = k + j * 16;
      float4 v = *(const float4*)(src + (size_t)kk * N + n4);
      int sw = kk & 31;
      t32[kk * 64 + ((n4 + 0) ^ sw)] = v.x;
      t32[kk * 64 + ((n4 + 1) ^ sw)] = v.y;
      t32[kk * 64 + ((n4 + 2) ^ sw)] = v.z;
      t32[kk * 64 + ((n4 + 3) ^ sw)] = v.w;
    }
    __syncthreads();
    unsigned short* dst = img + (size_t)((e * NB + nblk) * KB + kblk) * 4096;
#pragma unroll
    for (int c = 0; c < 2; c++) {
      int ci = t + c * 256;
      int col = ci >> 3, q = ci & 7, k8 = q ^ (col & 7);
      float f[8];
#pragma unroll
      for (int j = 0; j < 8; j++) {
        int kk = k8 * 8 + j;
        f[j] = t32[kk * 64 + (col ^ (kk & 31))];
      }
      uint4 o;
      o.x = pk2(f[0], f[1]);
      o.y = pk2(f[2], f[3]);
      o.z = pk2(f[4], f[5]);
      o.w = pk2(f[6], f[7]);
      *(uint4*)(dst + ci * 8) = o;
    }
    __syncthreads();
  }
}

// Image GEMM: tile 128x64, BK=64, 4 waves (2x2, each 64x32).
// BOTH operands via global_load_lds; double-buffered LDS, 2 raw barriers/iter,
// counted s_waitcnt vmcnt(6) (T4 -- never drains in the loop).
// LAYER 1: A=h16, B=img(w1), exact-GELU -> hid (bf16)
// LAYER 2: A=hid, B=img(w2), (+b2)*wgt  -> out (f32)
template <int LAYER>
__global__ __launch_bounds__(256, 3) void k_gemm_img(
    const unsigned short* __restrict__ Xb, const unsigned short* __restrict__ img,
    const float* __restrict__ Bias, const float* __restrict__ wgt,
    unsigned short* __restrict__ outB, float* __restrict__ outF,
    const int* __restrict__ wsI, const int* __restrict__ list) {
  constexpr int K = (LAYER == 1) ? DDIM : FDIM;
  constexpr int N = (LAYER == 1) ? FDIM : DDIM;
  constexpr int NIT = K / 64;
  constexpr int KB = K / 64, NB = N / 64;

  const int* cnt = wsI;
  const int* ntl = wsI + 48;
  const int* tiles = wsI + 64;

  int tI = blockIdx.y;
  if (tI >= *ntl) return;
  int e = tiles[2 * tI], m0 = tiles[2 * tI + 1];
  int rows = cnt[e] - m0;
  int base = e * NTOK + m0;
  int n0 = blockIdx.x * 64;

  __shared__ char sA[2][16384];  // bf16 [128][64], XOR-swizzled via source
  __shared__ char sB[2][8192];   // bf16 [64][64], image bytes == swizzled layout
  __shared__ int tokL[128];
  __shared__ float wgtL[128];

  int tid = threadIdx.x;
  if (tid < 128) {
    int tok = list[base + tid] & (NTOK - 1);  // pad slots clamp to a valid token
    tokL[tid] = tok;
    if (LAYER == 2) wgtL[tid] = wgt[tok];
  }
  __syncthreads();

  int lane = tid & 63, wid = tid >> 6, wm = wid >> 1, wn = wid & 1;

  // A source: per-lane pre-swizzled; dest = wave-uniform chunk base (+lane*16 HW)
  const char* gA[4];
  {
    unsigned sw = (unsigned)(((lane & 7) * 16) ^ ((lane >> 3) << 4));
#pragma unroll
    for (int j = 0; j < 4; j++) {
      int row = wid * 32 + j * 8 + (lane >> 3);
      gA[j] = (const char*)(Xb + (size_t)tokL[row] * K) + sw;
    }
  }
  // B source: linear per-lane walk through this (e, n-block)'s image tiles
  const char* gB = (const char*)img +
                   (size_t)((e * NB + (n0 >> 6)) * KB) * 8192 + wid * 2048 + lane * 16;

  floatx4 acc[4][2];
#pragma unroll
  for (int i = 0; i < 4; i++)
#pragma unroll
    for (int j = 0; j < 2; j++) acc[i][j] = (floatx4){0.f, 0.f, 0.f, 0.f};

#define GLOAD_AB(it, p)                                                     \
  do {                                                                      \
    _Pragma("unroll") for (int j = 0; j < 4; j++)                           \
        gload16(gA[j] + (size_t)(it) * 128, sA[p] + (wid * 4 + j) * 1024);  \
    _Pragma("unroll") for (int j = 0; j < 2; j++)                           \
        gload16(gB + (size_t)(it) * 8192 + j * 1024,                        \
                sB[p] + wid * 2048 + j * 1024);                             \
  } while (0)

#define MFMA_PHASE(P)                                                                    \
  do {                                                                                   \
    const char* A_ = sA[P];                                                              \
    const char* B_ = sB[P];                                                              \
    _Pragma("unroll") for (int kc = 0; kc < 2; kc++) {                                   \
      short8 af[4], bf[2];                                                               \
      int kb = kc * 64 + ((lane >> 4) << 4);                                             \
      _Pragma("unroll") for (int f = 0; f < 4; f++) {                                    \
        int rr = wm * 64 + f * 16 + (lane & 15);                                         \
        af[f] = *(const short8*)(A_ + rr * 128 + (kb ^ ((rr & 7) << 4)));                \
      }                                                                                  \
      _Pragma("unroll") for (int f = 0; f < 2; f++) {                                    \
        int cc = wn * 32 + f * 16 + (lane & 15);                                         \
        bf[f] = *(const short8*)(B_ + cc * 128 + (kb ^ ((cc & 7) << 4)));                \
      }                                                                                  \
      _Pragma("unroll") for (int fm = 0; fm < 4; fm++)                                   \
      _Pragma("unroll") for (int fn = 0; fn < 2; fn++)                                   \
          acc[fm][fn] =                                                                  \
              __builtin_amdgcn_mfma_f32_16x16x32_bf16(af[fm], bf[fn], acc[fm][fn], 0, 0, 0); \
    }                                                                                    \
  } while (0)

  GLOAD_AB(0, 0);
  for (int it = 0; it < NIT - 1; ++it) {
    int p = it & 1;
    __builtin_amdgcn_sched_barrier(0);
    __builtin_amdgcn_s_barrier();  // all reads of buf p^1 (iter it-1) done
    GLOAD_AB(it + 1, p ^ 1);
    __builtin_amdgcn_sched_barrier(0);
    asm volatile("s_waitcnt vmcnt(6)" ::: "memory");  // iter-it loads landed
    __builtin_amdgcn_s_barrier();
    __builtin_amdgcn_sched_barrier(0);
    MFMA_PHASE(p);
  }
  {
    int p = (NIT - 1) & 1;
    __builtin_amdgcn_sched_barrier(0);
    __builtin_amdgcn_s_barrier();
    asm volatile("s_waitcnt vmcnt(0)" ::: "memory");
    __builtin_amdgcn_s_barrier();
    __builtin_amdgcn_sched_barrier(0);
    MFMA_PHASE(p);
  }
#undef GLOAD_AB
#undef MFMA_PHASE

  // epilogue. C frag mapping: col = lane&15, row = (lane>>4)*4 + r
  float bv[2];
#pragma unroll
  for (int f = 0; f < 2; f++) bv[f] = Bias[(size_t)e * N + n0 + wn * 32 + f * 16 + (lane & 15)];
#pragma unroll
  for (int fm = 0; fm < 4; fm++) {
#pragma unroll
    for (int r = 0; r < 4; r++) {
      int gr = wm * 64 + fm * 16 + ((lane >> 4) << 2) + r;
      if (gr < rows) {
        int tok = tokL[gr];
#pragma unroll
        for (int fn = 0; fn < 2; fn++) {
          int col = n0 + wn * 32 + fn * 16 + (lane & 15);
          float v = acc[fm][fn][r] + bv[fn];
          if (LAYER == 1) {
            v = 0.5f * v * (1.0f + erff(v * 0.70710678118654752f));  // exact GELU
            outB[(size_t)tok * FDIM + col] = (unsigned short)bfr(v);
          } else {
            outF[(size_t)tok * DDIM + col] = v * wgtL[gr];
          }
        }
      }
    }
  }
}

extern "C" void kernel_launch(void* const* d_in, const int* in_sizes, int n_in,
                              void* d_out, int out_size, void* d_ws, size_t ws_size,
                              hipStream_t stream) {
  const float* h  = (const float*)d_in[0];
  const float* rw = (const float*)d_in[1];
  const float* w1 = (const float*)d_in[2];
  const float* b1 = (const float*)d_in[3];
  const float* w2 = (const float*)d_in[4];
  const float* b2 = (const float*)d_in[5];
  float* out = (float*)d_out;

  int* wsI = (int*)d_ws;
  float* wgt = (float*)(wsI + 4256);
  int* list = (int*)((char*)d_ws + 65536);                       // 14 x 4096 ints
  float* rwT = (float*)((char*)d_ws + 294912);                   // 57KB
  unsigned short* hid  = (unsigned short*)((char*)d_ws + 393216);    // 16.78MB
  unsigned short* h16  = (unsigned short*)((char*)d_ws + 17170432);  // 8.39MB
  unsigned short* img1 = (unsigned short*)((char*)d_ws + 25559040);  // 29.36MB
  unsigned short* img2 = (unsigned short*)((char*)d_ws + 17170432);  // overlays h16

  k_init<<<56, 256, 0, stream>>>(rw, rwT, wsI);
  k_router<<<NTOK / 4, 256, 0, stream>>>(h, rwT, wgt, wsI, list, h16);
  k_tiles<<<1, 64, 0, stream>>>(wsI, wsI + 64, wsI + 48);
  // image path: prep(w1) -> L1 -> prep(w2, overlaying h16) -> L2
  k_prep<<<NEXP * (FDIM / 64) * (DDIM / 64 / 4), 256, 0, stream>>>(w1, img1, DDIM, FDIM);
  k_gemm_img<1><<<dim3(FDIM / 64, 45), 256, 0, stream>>>(h16, img1, b1, nullptr, hid, nullptr, wsI, list);
  k_prep<<<NEXP * (DDIM / 64) * (FDIM / 64 / 4), 256, 0, stream>>>(w2, img2, FDIM, DDIM);
  k_gemm_img<2><<<dim3(DDIM / 64, 45), 256, 0, stream>>>(hid, img2, b2, wgt, nullptr, out, wsI, list);
}

// Round 10
// 188.647 us; speedup vs baseline: 1.2266x; 1.1768x over previous
//
#include <hip/hip_runtime.h>
#include <hip/hip_bf16.h>

// Problem: B=2,S=2048,D=1024,E=14,F=2048; N=4096 tokens.
// ws layout (bytes):
//   [0)      ints: cnt[0..14) @0, ntl @ int48, tiles @ int64..160,
//            assign @ int160..4256, wgt(f32) @ int4256..8352
//   [65536)  list: 14 regions x 4096 ints (224KB)
//   [294912) rwT: transposed router_w (14x1024 f32, 57KB)
//   [393216) hid bf16 (16.78MB)
//   [17170432) h16 bf16 (8.39MB)   -- dead after gemm1; img2 overlays it
//   [25559040) img1 (29.36MB)      -- swizzled bf16 w1 tile images
//   img2 @17170432 (29.36MB)       -- written by prep2 after gemm1
// total need: 54919168 bytes (harness provides >= 83.9MB, proven R8)

#define NTOK 4096
#define NEXP 14
#define DDIM 1024
#define FDIM 2048

typedef __attribute__((ext_vector_type(8))) short short8;
typedef __attribute__((ext_vector_type(4))) float floatx4;

__device__ __forceinline__ unsigned bfr(float f) {  // f32 -> bf16 bits, RNE
  unsigned u = __float_as_uint(f);
  return (u + 0x7FFFu + ((u >> 16) & 1u)) >> 16;
}
__device__ __forceinline__ unsigned pk2(float a, float b) {
  return bfr(a) | (bfr(b) << 16);
}

__device__ __forceinline__ void gload16(const void* g, void* l) {
  __builtin_amdgcn_global_load_lds((const __attribute__((address_space(1))) void*)g,
                                   (__attribute__((address_space(3))) void*)l, 16, 0, 0);
}

// build transposed router weights rwT[e][d]
__global__ void k_init(const float* __restrict__ rw, float* __restrict__ rwT) {
  int i = blockIdx.x * 256 + threadIdx.x;
  if (i < DDIM * NEXP) rwT[(i % NEXP) * DDIM + i / NEXP] = rw[i];
}

// one wave per token, NO LDS, NO ATOMICS: fp64 logits from coalesced float4
// reads, butterfly allreduce, all-lane fp32 softmax tail. Emits h16 = bf16(h).
__global__ __launch_bounds__(256) void k_router(
    const float* __restrict__ x, const float* __restrict__ rwT,
    int* __restrict__ assign, float* __restrict__ wgt,
    unsigned short* __restrict__ h16) {
  int wid = threadIdx.x >> 6, lane = threadIdx.x & 63;
  int n = blockIdx.x * 4 + wid;
  const float* xr = x + (size_t)n * DDIM;
  unsigned short* hr = h16 + (size_t)n * DDIM;
  double acc[NEXP];
#pragma unroll
  for (int e = 0; e < NEXP; e++) acc[e] = 0.0;
#pragma unroll
  for (int i = 0; i < 4; i++) {
    int d0 = i * 256 + lane * 4;
    float4 xv = *(const float4*)(xr + d0);
    uint2 hb;
    hb.x = pk2(xv.x, xv.y);
    hb.y = pk2(xv.z, xv.w);
    *(uint2*)(hr + d0) = hb;
    double x0 = xv.x, x1 = xv.y, x2 = xv.z, x3 = xv.w;
#pragma unroll
    for (int e = 0; e < NEXP; e++) {
      float4 rv = *(const float4*)(rwT + e * DDIM + d0);
      acc[e] += x0 * (double)rv.x + x1 * (double)rv.y + x2 * (double)rv.z + x3 * (double)rv.w;
    }
  }
#pragma unroll
  for (int e = 0; e < NEXP; e++)
    for (int m = 32; m > 0; m >>= 1) acc[e] += __shfl_xor(acc[e], m, 64);
  int best = 0;
  double bv = acc[0];
#pragma unroll
  for (int e = 1; e < NEXP; e++)
    if (acc[e] > bv) { bv = acc[e]; best = e; }
  float s = 0.f;
#pragma unroll
  for (int e = 0; e < NEXP; e++) s += expf((float)(acc[e] - bv));
  if (lane == 0) {
    wgt[n] = 1.0f / s;
    assign[n] = best;
  }
}

// single block, 1024 threads: ballot-based stable counting sort, no atomics.
// group = (wave, t) handles tokens n = wave*256 + t*64 + lane.
// Pass 1: per-group per-expert counts (ballot+popcount) + per-token rank.
// Scan:   wave w (<14) scans expert w's counts over the 64 groups.
// Pass 2: scatter list[e*4096 + groupPrefix + rank] = n.
// Tail:   wave 15 builds tile descriptors (fused old k_tiles).
__global__ __launch_bounds__(1024) void k_sort(
    const int* __restrict__ assign, int* __restrict__ cnt,
    int* __restrict__ list, int* __restrict__ tiles, int* __restrict__ ntl) {
  __shared__ int clds[64][NEXP];  // [group][expert]
  __shared__ int tot[16];
  __shared__ int tstart[NEXP + 1];
  int tid = threadIdx.x;
  int wv = tid >> 6, lane = tid & 63;
  unsigned long long below = (1ull << lane) - 1ull;
  int e4[4], r4[4];
#pragma unroll
  for (int t = 0; t < 4; t++) {
    int n = wv * 256 + t * 64 + lane;
    int e = assign[n];
    int rank = 0, gcnt = 0;
#pragma unroll
    for (int xx = 0; xx < NEXP; xx++) {
      unsigned long long m = __ballot(e == xx);
      if (e == xx) rank = __popcll(m & below);
      if (lane == xx) gcnt = __popcll(m);
    }
    e4[t] = e;
    r4[t] = rank;
    if (lane < NEXP) clds[wv * 4 + t][lane] = gcnt;
  }
  __syncthreads();
  if (wv < NEXP) {  // wave wv scans expert wv over 64 groups
    int v = clds[lane][wv];
    int s = v;
    for (int m = 1; m < 64; m <<= 1) {
      int t = __shfl_up(s, m, 64);
      if (lane >= m) s += t;
    }
    clds[lane][wv] = s - v;  // exclusive prefix
    if (lane == 63) {
      cnt[wv] = s;
      tot[wv] = s;
    }
  }
  __syncthreads();
#pragma unroll
  for (int t = 0; t < 4; t++) {
    int n = wv * 256 + t * 64 + lane;
    int e = e4[t];
    int pos = clds[wv * 4 + t][e] + r4[t];
    list[e * NTOK + pos] = n;
  }
  if (wv == 15) {  // tile descriptors
    int c = (lane < NEXP) ? tot[lane] : 0;
    int nt = (c + 127) >> 7;
    int st = nt;
    for (int m = 1; m < 64; m <<= 1) {
      int t = __shfl_up(st, m, 64);
      if (lane >= m) st += t;
    }
    if (lane < NEXP) tstart[lane] = st - nt;
    if (lane == NEXP - 1) {
      tstart[NEXP] = st;
      *ntl = st;
    }
    int totT = __shfl(st, NEXP - 1, 64);
    if (lane < totT) {
      int e = 0;
      while (tstart[e + 1] <= lane) e++;
      tiles[2 * lane] = e;
      tiles[2 * lane + 1] = (lane - tstart[e]) * 128;
    }
  }
}

// Weight-image pre-pass, 4 k-tiles per block (z-loop).
// Emits the exact byte image of the GEMM's swizzled LDS B-tile:
//   chunk ci = col*8 + (k8 ^ (col&7)); bytes = bf16 W[k8*8+j][col], j=0..7.
// LDS f32 transpose tile dword-swizzled: dw = k*64 + (n ^ (k&31)).
__global__ __launch_bounds__(256) void k_prep(const float* __restrict__ W,
                                              unsigned short* __restrict__ img,
                                              int K, int N) {
  __shared__ float t32[4096];
  int KB = K >> 6, NB = N >> 6, K4 = KB >> 2;
  int b = blockIdx.x;
  int kb4 = b % K4;
  int nb_ = b / K4;
  int nblk = nb_ % NB, e = nb_ / NB;
  int t = threadIdx.x;
  int k = t >> 4, n4 = (t & 15) * 4;
  for (int z = 0; z < 4; z++) {
    int kblk = kb4 * 4 + z;
    const float* src = W + (size_t)e * K * N + (size_t)(kblk * 64) * N + nblk * 64;
#pragma unroll
    for (int j = 0; j < 4; j++) {
      int kk = k + j * 16;
      float4 v = *(const float4*)(src + (size_t)kk * N + n4);
      int sw = kk & 31;
      t32[kk * 64 + ((n4 + 0) ^ sw)] = v.x;
      t32[kk * 64 + ((n4 + 1) ^ sw)] = v.y;
      t32[kk * 64 + ((n4 + 2) ^ sw)] = v.z;
      t32[kk * 64 + ((n4 + 3) ^ sw)] = v.w;
    }
    __syncthreads();
    unsigned short* dst = img + (size_t)((e * NB + nblk) * KB + kblk) * 4096;
#pragma unroll
    for (int c = 0; c < 2; c++) {
      int ci = t + c * 256;
      int col = ci >> 3, q = ci & 7, k8 = q ^ (col & 7);
      float f[8];
#pragma unroll
      for (int j = 0; j < 8; j++) {
        int kk = k8 * 8 + j;
        f[j] = t32[kk * 64 + (col ^ (kk & 31))];
      }
      uint4 o;
      o.x = pk2(f[0], f[1]);
      o.y = pk2(f[2], f[3]);
      o.z = pk2(f[4], f[5]);
      o.w = pk2(f[6], f[7]);
      *(uint4*)(dst + ci * 8) = o;
    }
    __syncthreads();
  }
}

// Image GEMM: tile 128x64, BK=64, 4 waves (2x2, each 64x32).
// BOTH operands via global_load_lds; double-buffered LDS, 2 raw barriers/iter,
// counted s_waitcnt vmcnt(6) (T4 -- never drains in the loop).
// LAYER 1: A=h16, B=img(w1), exact-GELU -> hid (bf16)
// LAYER 2: A=hid, B=img(w2), (+b2)*wgt  -> out (f32)
template <int LAYER>
__global__ __launch_bounds__(256, 3) void k_gemm_img(
    const unsigned short* __restrict__ Xb, const unsigned short* __restrict__ img,
    const float* __restrict__ Bias, const float* __restrict__ wgt,
    unsigned short* __restrict__ outB, float* __restrict__ outF,
    const int* __restrict__ wsI, const int* __restrict__ list) {
  constexpr int K = (LAYER == 1) ? DDIM : FDIM;
  constexpr int N = (LAYER == 1) ? FDIM : DDIM;
  constexpr int NIT = K / 64;
  constexpr int KB = K / 64, NB = N / 64;

  const int* cnt = wsI;
  const int* ntl = wsI + 48;
  const int* tiles = wsI + 64;

  int tI = blockIdx.y;
  if (tI >= *ntl) return;
  int e = tiles[2 * tI], m0 = tiles[2 * tI + 1];
  int rows = cnt[e] - m0;
  int base = e * NTOK + m0;
  int n0 = blockIdx.x * 64;

  __shared__ char sA[2][16384];  // bf16 [128][64], XOR-swizzled via source
  __shared__ char sB[2][8192];   // bf16 [64][64], image bytes == swizzled layout
  __shared__ int tokL[128];
  __shared__ float wgtL[128];

  int tid = threadIdx.x;
  if (tid < 128) {
    int tok = list[base + tid] & (NTOK - 1);  // pad slots clamp to a valid token
    tokL[tid] = tok;
    if (LAYER == 2) wgtL[tid] = wgt[tok];
  }
  __syncthreads();

  int lane = tid & 63, wid = tid >> 6, wm = wid >> 1, wn = wid & 1;

  // A source: per-lane pre-swizzled; dest = wave-uniform chunk base (+lane*16 HW)
  const char* gA[4];
  {
    unsigned sw = (unsigned)(((lane & 7) * 16) ^ ((lane >> 3) << 4));
#pragma unroll
    for (int j = 0; j < 4; j++) {
      int row = wid * 32 + j * 8 + (lane >> 3);
      gA[j] = (const char*)(Xb + (size_t)tokL[row] * K) + sw;
    }
  }
  // B source: linear per-lane walk through this (e, n-block)'s image tiles
  const char* gB = (const char*)img +
                   (size_t)((e * NB + (n0 >> 6)) * KB) * 8192 + wid * 2048 + lane * 16;

  floatx4 acc[4][2];
#pragma unroll
  for (int i = 0; i < 4; i++)
#pragma unroll
    for (int j = 0; j < 2; j++) acc[i][j] = (floatx4){0.f, 0.f, 0.f, 0.f};

#define GLOAD_AB(it, p)                                                     \
  do {                                                                      \
    _Pragma("unroll") for (int j = 0; j < 4; j++)                           \
        gload16(gA[j] + (size_t)(it) * 128, sA[p] + (wid * 4 + j) * 1024);  \
    _Pragma("unroll") for (int j = 0; j < 2; j++)                           \
        gload16(gB + (size_t)(it) * 8192 + j * 1024,                        \
                sB[p] + wid * 2048 + j * 1024);                             \
  } while (0)

#define MFMA_PHASE(P)                                                                    \
  do {                                                                                   \
    const char* A_ = sA[P];                                                              \
    const char* B_ = sB[P];                                                              \
    _Pragma("unroll") for (int kc = 0; kc < 2; kc++) {                                   \
      short8 af[4], bf[2];                                                               \
      int kb = kc * 64 + ((lane >> 4) << 4);                                             \
      _Pragma("unroll") for (int f = 0; f < 4; f++) {                                    \
        int rr = wm * 64 + f * 16 + (lane & 15);                                         \
        af[f] = *(const short8*)(A_ + rr * 128 + (kb ^ ((rr & 7) << 4)));                \
      }                                                                                  \
      _Pragma("unroll") for (int f = 0; f < 2; f++) {                                    \
        int cc = wn * 32 + f * 16 + (lane & 15);                                         \
        bf[f] = *(const short8*)(B_ + cc * 128 + (kb ^ ((cc & 7) << 4)));                \
      }                                                                                  \
      _Pragma("unroll") for (int fm = 0; fm < 4; fm++)                                   \
      _Pragma("unroll") for (int fn = 0; fn < 2; fn++)                                   \
          acc[fm][fn] =                                                                  \
              __builtin_amdgcn_mfma_f32_16x16x32_bf16(af[fm], bf[fn], acc[fm][fn], 0, 0, 0); \
    }                                                                                    \
  } while (0)

  GLOAD_AB(0, 0);
  for (int it = 0; it < NIT - 1; ++it) {
    int p = it & 1;
    __builtin_amdgcn_sched_barrier(0);
    __builtin_amdgcn_s_barrier();  // all reads of buf p^1 (iter it-1) done
    GLOAD_AB(it + 1, p ^ 1);
    __builtin_amdgcn_sched_barrier(0);
    asm volatile("s_waitcnt vmcnt(6)" ::: "memory");  // iter-it loads landed
    __builtin_amdgcn_s_barrier();
    __builtin_amdgcn_sched_barrier(0);
    MFMA_PHASE(p);
  }
  {
    int p = (NIT - 1) & 1;
    __builtin_amdgcn_sched_barrier(0);
    __builtin_amdgcn_s_barrier();
    asm volatile("s_waitcnt vmcnt(0)" ::: "memory");
    __builtin_amdgcn_s_barrier();
    __builtin_amdgcn_sched_barrier(0);
    MFMA_PHASE(p);
  }
#undef GLOAD_AB
#undef MFMA_PHASE

  // epilogue. C frag mapping: col = lane&15, row = (lane>>4)*4 + r
  float bv[2];
#pragma unroll
  for (int f = 0; f < 2; f++) bv[f] = Bias[(size_t)e * N + n0 + wn * 32 + f * 16 + (lane & 15)];
#pragma unroll
  for (int fm = 0; fm < 4; fm++) {
#pragma unroll
    for (int r = 0; r < 4; r++) {
      int gr = wm * 64 + fm * 16 + ((lane >> 4) << 2) + r;
      if (gr < rows) {
        int tok = tokL[gr];
#pragma unroll
        for (int fn = 0; fn < 2; fn++) {
          int col = n0 + wn * 32 + fn * 16 + (lane & 15);
          float v = acc[fm][fn][r] + bv[fn];
          if (LAYER == 1) {
            v = 0.5f * v * (1.0f + erff(v * 0.70710678118654752f));  // exact GELU
            outB[(size_t)tok * FDIM + col] = (unsigned short)bfr(v);
          } else {
            outF[(size_t)tok * DDIM + col] = v * wgtL[gr];
          }
        }
      }
    }
  }
}

extern "C" void kernel_launch(void* const* d_in, const int* in_sizes, int n_in,
                              void* d_out, int out_size, void* d_ws, size_t ws_size,
                              hipStream_t stream) {
  const float* h  = (const float*)d_in[0];
  const float* rw = (const float*)d_in[1];
  const float* w1 = (const float*)d_in[2];
  const float* b1 = (const float*)d_in[3];
  const float* w2 = (const float*)d_in[4];
  const float* b2 = (const float*)d_in[5];
  float* out = (float*)d_out;

  int* wsI = (int*)d_ws;
  int* assign = wsI + 160;
  float* wgt = (float*)(wsI + 4256);
  int* list = (int*)((char*)d_ws + 65536);                       // 14 x 4096 ints
  float* rwT = (float*)((char*)d_ws + 294912);                   // 57KB
  unsigned short* hid  = (unsigned short*)((char*)d_ws + 393216);    // 16.78MB
  unsigned short* h16  = (unsigned short*)((char*)d_ws + 17170432);  // 8.39MB
  unsigned short* img1 = (unsigned short*)((char*)d_ws + 25559040);  // 29.36MB
  unsigned short* img2 = (unsigned short*)((char*)d_ws + 17170432);  // overlays h16

  k_init<<<56, 256, 0, stream>>>(rw, rwT);
  k_router<<<NTOK / 4, 256, 0, stream>>>(h, rwT, assign, wgt, h16);
  k_sort<<<1, 1024, 0, stream>>>(assign, wsI, list, wsI + 64, wsI + 48);
  // image path: prep(w1) -> L1 -> prep(w2, overlaying h16) -> L2
  k_prep<<<NEXP * (FDIM / 64) * (DDIM / 64 / 4), 256, 0, stream>>>(w1, img1, DDIM, FDIM);
  k_gemm_img<1><<<dim3(FDIM / 64, 45), 256, 0, stream>>>(h16, img1, b1, nullptr, hid, nullptr, wsI, list);
  k_prep<<<NEXP * (DDIM / 64) * (FDIM / 64 / 4), 256, 0, stream>>>(w2, img2, FDIM, DDIM);
  k_gemm_img<2><<<dim3(DDIM / 64, 45), 256, 0, stream>>>(hid, img2, b2, wgt, nullptr, out, wsI, list);
}

// Round 11
// 167.088 us; speedup vs baseline: 1.3849x; 1.1290x over previous
//
#include <hip/hip_runtime.h>
#include <hip/hip_bf16.h>

// Problem: B=2,S=2048,D=1024,E=14,F=2048; N=4096 tokens.
// ws layout (bytes), ws_size ~= 448MB (observed via harness poison fill):
//   [0)        ints: cnt[0..14) @0, ntl @ int48, tiles @ int64..160,
//              assign @ int160..4256, wgt(f32) @ int4256..8352
//   [65536)    list: 14 regions x 4096 ints (224KB)
//   [294912)   rwT: transposed router_w (14x1024 f32, 57KB)
//   [393216)   hid bf16 (16.78MB)
//   [17170432) h16 bf16 (8.39MB)        -- live through gemm1 (no overlay now)
//   [25559040) img1 (29.36MB)           -- swizzled bf16 w1 tile images
//   [54919168) img2 (29.36MB)           -- swizzled bf16 w2 tile images
// total need: 84279296 bytes.
//
// Launch graph (5 dispatches):
//   k_init -> k_fuseA{router || prep(w1)} -> k_sort
//          -> k_fuseB{gemm1 || prep(w2)} -> k_gemm2

#define NTOK 4096
#define NEXP 14
#define DDIM 1024
#define FDIM 2048

typedef __attribute__((ext_vector_type(8))) short short8;
typedef __attribute__((ext_vector_type(4))) float floatx4;

__device__ __forceinline__ unsigned bfr(float f) {  // f32 -> bf16 bits, RNE
  unsigned u = __float_as_uint(f);
  return (u + 0x7FFFu + ((u >> 16) & 1u)) >> 16;
}
__device__ __forceinline__ unsigned pk2(float a, float b) {
  return bfr(a) | (bfr(b) << 16);
}

__device__ __forceinline__ void gload16(const void* g, void* l) {
  __builtin_amdgcn_global_load_lds((const __attribute__((address_space(1))) void*)g,
                                   (__attribute__((address_space(3))) void*)l, 16, 0, 0);
}

struct GemmSh {
  char sA[2][16384];  // bf16 [128][64], XOR-swizzled via source
  char sB[2][8192];   // bf16 [64][64], image bytes == swizzled layout
  int tokL[128];
  float wgtL[128];
};
union FuseSh {
  GemmSh g;
  float t32[4096];
};

// build transposed router weights rwT[e][d]
__global__ void k_init(const float* __restrict__ rw, float* __restrict__ rwT) {
  int i = blockIdx.x * 256 + threadIdx.x;
  if (i < DDIM * NEXP) rwT[(i % NEXP) * DDIM + i / NEXP] = rw[i];
}

// ---- router body: one wave per token, no LDS, no atomics ----
__device__ __forceinline__ void router_body(
    int bid, const float* __restrict__ x, const float* __restrict__ rwT,
    int* __restrict__ assign, float* __restrict__ wgt,
    unsigned short* __restrict__ h16) {
  int wid = threadIdx.x >> 6, lane = threadIdx.x & 63;
  int n = bid * 4 + wid;
  const float* xr = x + (size_t)n * DDIM;
  unsigned short* hr = h16 + (size_t)n * DDIM;
  double acc[NEXP];
#pragma unroll
  for (int e = 0; e < NEXP; e++) acc[e] = 0.0;
#pragma unroll
  for (int i = 0; i < 4; i++) {
    int d0 = i * 256 + lane * 4;
    float4 xv = *(const float4*)(xr + d0);
    uint2 hb;
    hb.x = pk2(xv.x, xv.y);
    hb.y = pk2(xv.z, xv.w);
    *(uint2*)(hr + d0) = hb;
    double x0 = xv.x, x1 = xv.y, x2 = xv.z, x3 = xv.w;
#pragma unroll
    for (int e = 0; e < NEXP; e++) {
      float4 rv = *(const float4*)(rwT + e * DDIM + d0);
      acc[e] += x0 * (double)rv.x + x1 * (double)rv.y + x2 * (double)rv.z + x3 * (double)rv.w;
    }
  }
#pragma unroll
  for (int e = 0; e < NEXP; e++)
    for (int m = 32; m > 0; m >>= 1) acc[e] += __shfl_xor(acc[e], m, 64);
  int best = 0;
  double bv = acc[0];
#pragma unroll
  for (int e = 1; e < NEXP; e++)
    if (acc[e] > bv) { bv = acc[e]; best = e; }
  float s = 0.f;
#pragma unroll
  for (int e = 0; e < NEXP; e++) s += expf((float)(acc[e] - bv));
  if (lane == 0) {
    wgt[n] = 1.0f / s;
    assign[n] = best;
  }
}

// ---- weight-image prep body: 4 k-tiles per block (z-loop) ----
// Emits exact byte image of the GEMM's swizzled LDS B-tile:
//   chunk ci = col*8 + (k8 ^ (col&7)); bytes = bf16 W[k8*8+j][col], j=0..7.
// LDS f32 transpose tile dword-swizzled: dw = k*64 + (n ^ (k&31)).
__device__ __forceinline__ void prep_body(float* __restrict__ t32,
                                          const float* __restrict__ W,
                                          unsigned short* __restrict__ img,
                                          int K, int N, int b) {
  int KB = K >> 6, NB = N >> 6, K4 = KB >> 2;
  int kb4 = b % K4;
  int nb_ = b / K4;
  int nblk = nb_ % NB, e = nb_ / NB;
  int t = threadIdx.x;
  int k = t >> 4, n4 = (t & 15) * 4;
  for (int z = 0; z < 4; z++) {
    int kblk = kb4 * 4 + z;
    const float* src = W + (size_t)e * K * N + (size_t)(kblk * 64) * N + nblk * 64;
#pragma unroll
    for (int j = 0; j < 4; j++) {
      int kk = k + j * 16;
      float4 v = *(const float4*)(src + (size_t)kk * N + n4);
      int sw = kk & 31;
      t32[kk * 64 + ((n4 + 0) ^ sw)] = v.x;
      t32[kk * 64 + ((n4 + 1) ^ sw)] = v.y;
      t32[kk * 64 + ((n4 + 2) ^ sw)] = v.z;
      t32[kk * 64 + ((n4 + 3) ^ sw)] = v.w;
    }
    __syncthreads();
    unsigned short* dst = img + (size_t)((e * NB + nblk) * KB + kblk) * 4096;
#pragma unroll
    for (int c = 0; c < 2; c++) {
      int ci = t + c * 256;
      int col = ci >> 3, q = ci & 7, k8 = q ^ (col & 7);
      float f[8];
#pragma unroll
      for (int j = 0; j < 8; j++) {
        int kk = k8 * 8 + j;
        f[j] = t32[kk * 64 + (col ^ (kk & 31))];
      }
      uint4 o;
      o.x = pk2(f[0], f[1]);
      o.y = pk2(f[2], f[3]);
      o.z = pk2(f[4], f[5]);
      o.w = pk2(f[6], f[7]);
      *(uint4*)(dst + ci * 8) = o;
    }
    __syncthreads();
  }
}

// ---- image-GEMM body: tile 128x64, BK=64, 4 waves (2x2, each 64x32) ----
// BOTH operands via global_load_lds; double-buffered LDS, 2 raw barriers/iter,
// counted s_waitcnt vmcnt(6) (T4 -- never drains in the loop).
template <int LAYER>
__device__ __forceinline__ void gemm_body(
    GemmSh* sh, int tI, int n0,
    const unsigned short* __restrict__ Xb, const unsigned short* __restrict__ img,
    const float* __restrict__ Bias, const float* __restrict__ wgt,
    unsigned short* __restrict__ outB, float* __restrict__ outF,
    const int* __restrict__ wsI, const int* __restrict__ list) {
  constexpr int K = (LAYER == 1) ? DDIM : FDIM;
  constexpr int N = (LAYER == 1) ? FDIM : DDIM;
  constexpr int NIT = K / 64;
  constexpr int KB = K / 64, NB = N / 64;

  const int* cnt = wsI;
  const int* ntl = wsI + 48;
  const int* tiles = wsI + 64;

  if (tI >= *ntl) return;
  int e = tiles[2 * tI], m0 = tiles[2 * tI + 1];
  int rows = cnt[e] - m0;
  int base = e * NTOK + m0;

  char (*sA)[16384] = sh->sA;
  char (*sB)[8192] = sh->sB;
  int* tokL = sh->tokL;
  float* wgtL = sh->wgtL;

  int tid = threadIdx.x;
  if (tid < 128) {
    int tok = list[base + tid] & (NTOK - 1);  // pad slots clamp to a valid token
    tokL[tid] = tok;
    if (LAYER == 2) wgtL[tid] = wgt[tok];
  }
  __syncthreads();

  int lane = tid & 63, wid = tid >> 6, wm = wid >> 1, wn = wid & 1;

  // A source: per-lane pre-swizzled; dest = wave-uniform chunk base (+lane*16 HW)
  const char* gA[4];
  {
    unsigned sw = (unsigned)(((lane & 7) * 16) ^ ((lane >> 3) << 4));
#pragma unroll
    for (int j = 0; j < 4; j++) {
      int row = wid * 32 + j * 8 + (lane >> 3);
      gA[j] = (const char*)(Xb + (size_t)tokL[row] * K) + sw;
    }
  }
  // B source: linear per-lane walk through this (e, n-block)'s image tiles
  const char* gB = (const char*)img +
                   (size_t)((e * NB + (n0 >> 6)) * KB) * 8192 + wid * 2048 + lane * 16;

  floatx4 acc[4][2];
#pragma unroll
  for (int i = 0; i < 4; i++)
#pragma unroll
    for (int j = 0; j < 2; j++) acc[i][j] = (floatx4){0.f, 0.f, 0.f, 0.f};

#define GLOAD_AB(it, p)                                                     \
  do {                                                                      \
    _Pragma("unroll") for (int j = 0; j < 4; j++)                           \
        gload16(gA[j] + (size_t)(it) * 128, sA[p] + (wid * 4 + j) * 1024);  \
    _Pragma("unroll") for (int j = 0; j < 2; j++)                           \
        gload16(gB + (size_t)(it) * 8192 + j * 1024,                        \
                sB[p] + wid * 2048 + j * 1024);                             \
  } while (0)

#define MFMA_PHASE(P)                                                                    \
  do {                                                                                   \
    const char* A_ = sA[P];                                                              \
    const char* B_ = sB[P];                                                              \
    _Pragma("unroll") for (int kc = 0; kc < 2; kc++) {                                   \
      short8 af[4], bf[2];                                                               \
      int kb = kc * 64 + ((lane >> 4) << 4);                                             \
      _Pragma("unroll") for (int f = 0; f < 4; f++) {                                    \
        int rr = wm * 64 + f * 16 + (lane & 15);                                         \
        af[f] = *(const short8*)(A_ + rr * 128 + (kb ^ ((rr & 7) << 4)));                \
      }                                                                                  \
      _Pragma("unroll") for (int f = 0; f < 2; f++) {                                    \
        int cc = wn * 32 + f * 16 + (lane & 15);                                         \
        bf[f] = *(const short8*)(B_ + cc * 128 + (kb ^ ((cc & 7) << 4)));                \
      }                                                                                  \
      _Pragma("unroll") for (int fm = 0; fm < 4; fm++)                                   \
      _Pragma("unroll") for (int fn = 0; fn < 2; fn++)                                   \
          acc[fm][fn] =                                                                  \
              __builtin_amdgcn_mfma_f32_16x16x32_bf16(af[fm], bf[fn], acc[fm][fn], 0, 0, 0); \
    }                                                                                    \
  } while (0)

  GLOAD_AB(0, 0);
  for (int it = 0; it < NIT - 1; ++it) {
    int p = it & 1;
    __builtin_amdgcn_sched_barrier(0);
    __builtin_amdgcn_s_barrier();  // all reads of buf p^1 (iter it-1) done
    GLOAD_AB(it + 1, p ^ 1);
    __builtin_amdgcn_sched_barrier(0);
    asm volatile("s_waitcnt vmcnt(6)" ::: "memory");  // iter-it loads landed
    __builtin_amdgcn_s_barrier();
    __builtin_amdgcn_sched_barrier(0);
    MFMA_PHASE(p);
  }
  {
    int p = (NIT - 1) & 1;
    __builtin_amdgcn_sched_barrier(0);
    __builtin_amdgcn_s_barrier();
    asm volatile("s_waitcnt vmcnt(0)" ::: "memory");
    __builtin_amdgcn_s_barrier();
    __builtin_amdgcn_sched_barrier(0);
    MFMA_PHASE(p);
  }
#undef GLOAD_AB
#undef MFMA_PHASE

  // epilogue. C frag mapping: col = lane&15, row = (lane>>4)*4 + r
  float bv[2];
#pragma unroll
  for (int f = 0; f < 2; f++) bv[f] = Bias[(size_t)e * N + n0 + wn * 32 + f * 16 + (lane & 15)];
#pragma unroll
  for (int fm = 0; fm < 4; fm++) {
#pragma unroll
    for (int r = 0; r < 4; r++) {
      int gr = wm * 64 + fm * 16 + ((lane >> 4) << 2) + r;
      if (gr < rows) {
        int tok = tokL[gr];
#pragma unroll
        for (int fn = 0; fn < 2; fn++) {
          int col = n0 + wn * 32 + fn * 16 + (lane & 15);
          float v = acc[fm][fn][r] + bv[fn];
          if (LAYER == 1) {
            v = 0.5f * v * (1.0f + erff(v * 0.70710678118654752f));  // exact GELU
            outB[(size_t)tok * FDIM + col] = (unsigned short)bfr(v);
          } else {
            outF[(size_t)tok * DDIM + col] = v * wgtL[gr];
          }
        }
      }
    }
  }
}

// ---- fused A: router (1024 blocks) || prep(w1) (1792 blocks) ----
__global__ __launch_bounds__(256) void k_fuseA(
    const float* __restrict__ x, const float* __restrict__ rwT,
    int* __restrict__ assign, float* __restrict__ wgt,
    unsigned short* __restrict__ h16,
    const float* __restrict__ w1, unsigned short* __restrict__ img1) {
  __shared__ float t32[4096];
  int bid = blockIdx.x;
  if (bid < NTOK / 4) {
    router_body(bid, x, rwT, assign, wgt, h16);
  } else {
    prep_body(t32, w1, img1, DDIM, FDIM, bid - NTOK / 4);
  }
}

// single block, 1024 threads: ballot-based stable counting sort, no atomics.
__global__ __launch_bounds__(1024) void k_sort(
    const int* __restrict__ assign, int* __restrict__ cnt,
    int* __restrict__ list, int* __restrict__ tiles, int* __restrict__ ntl) {
  __shared__ int clds[64][NEXP];
  __shared__ int tot[16];
  __shared__ int tstart[NEXP + 1];
  int tid = threadIdx.x;
  int wv = tid >> 6, lane = tid & 63;
  unsigned long long below = (1ull << lane) - 1ull;
  int e4[4], r4[4];
#pragma unroll
  for (int t = 0; t < 4; t++) {
    int n = wv * 256 + t * 64 + lane;
    int e = assign[n];
    int rank = 0, gcnt = 0;
#pragma unroll
    for (int xx = 0; xx < NEXP; xx++) {
      unsigned long long m = __ballot(e == xx);
      if (e == xx) rank = __popcll(m & below);
      if (lane == xx) gcnt = __popcll(m);
    }
    e4[t] = e;
    r4[t] = rank;
    if (lane < NEXP) clds[wv * 4 + t][lane] = gcnt;
  }
  __syncthreads();
  if (wv < NEXP) {
    int v = clds[lane][wv];
    int s = v;
    for (int m = 1; m < 64; m <<= 1) {
      int t = __shfl_up(s, m, 64);
      if (lane >= m) s += t;
    }
    clds[lane][wv] = s - v;
    if (lane == 63) {
      cnt[wv] = s;
      tot[wv] = s;
    }
  }
  __syncthreads();
#pragma unroll
  for (int t = 0; t < 4; t++) {
    int n = wv * 256 + t * 64 + lane;
    int e = e4[t];
    int pos = clds[wv * 4 + t][e] + r4[t];
    list[e * NTOK + pos] = n;
  }
  if (wv == 15) {
    int c = (lane < NEXP) ? tot[lane] : 0;
    int nt = (c + 127) >> 7;
    int st = nt;
    for (int m = 1; m < 64; m <<= 1) {
      int t = __shfl_up(st, m, 64);
      if (lane >= m) st += t;
    }
    if (lane < NEXP) tstart[lane] = st - nt;
    if (lane == NEXP - 1) {
      tstart[NEXP] = st;
      *ntl = st;
    }
    int totT = __shfl(st, NEXP - 1, 64);
    if (lane < totT) {
      int e = 0;
      while (tstart[e + 1] <= lane) e++;
      tiles[2 * lane] = e;
      tiles[2 * lane + 1] = (lane - tstart[e]) * 128;
    }
  }
}

// ---- fused B: gemm1 (1440 blocks, flat id keeps x32 -> same-XCD) || prep(w2) ----
__global__ __launch_bounds__(256, 3) void k_fuseB(
    const unsigned short* __restrict__ h16, const unsigned short* __restrict__ img1,
    const float* __restrict__ b1, unsigned short* __restrict__ hid,
    const int* __restrict__ wsI, const int* __restrict__ list,
    const float* __restrict__ w2, unsigned short* __restrict__ img2) {
  __shared__ FuseSh sh;
  int bid = blockIdx.x;
  if (bid < (FDIM / 64) * 45) {
    gemm_body<1>(&sh.g, bid >> 5, (bid & 31) << 6, h16, img1, b1, nullptr, hid,
                 nullptr, wsI, list);
  } else {
    prep_body(sh.t32, w2, img2, FDIM, DDIM, bid - (FDIM / 64) * 45);
  }
}

__global__ __launch_bounds__(256, 3) void k_gemm2(
    const unsigned short* __restrict__ hid, const unsigned short* __restrict__ img2,
    const float* __restrict__ b2, const float* __restrict__ wgt,
    float* __restrict__ outF, const int* __restrict__ wsI,
    const int* __restrict__ list) {
  __shared__ GemmSh sh;
  gemm_body<2>(&sh, blockIdx.y, blockIdx.x << 6, hid, img2, b2, wgt, nullptr,
               outF, wsI, list);
}

extern "C" void kernel_launch(void* const* d_in, const int* in_sizes, int n_in,
                              void* d_out, int out_size, void* d_ws, size_t ws_size,
                              hipStream_t stream) {
  const float* h  = (const float*)d_in[0];
  const float* rw = (const float*)d_in[1];
  const float* w1 = (const float*)d_in[2];
  const float* b1 = (const float*)d_in[3];
  const float* w2 = (const float*)d_in[4];
  const float* b2 = (const float*)d_in[5];
  float* out = (float*)d_out;

  int* wsI = (int*)d_ws;
  int* assign = wsI + 160;
  float* wgt = (float*)(wsI + 4256);
  int* list = (int*)((char*)d_ws + 65536);                           // 14 x 4096 ints
  float* rwT = (float*)((char*)d_ws + 294912);                       // 57KB
  unsigned short* hid  = (unsigned short*)((char*)d_ws + 393216);    // 16.78MB
  unsigned short* h16  = (unsigned short*)((char*)d_ws + 17170432);  // 8.39MB
  unsigned short* img1 = (unsigned short*)((char*)d_ws + 25559040);  // 29.36MB
  unsigned short* img2 = (unsigned short*)((char*)d_ws + 54919168);  // 29.36MB

  k_init<<<56, 256, 0, stream>>>(rw, rwT);
  // router (1024) || prep(w1) (14*32*4 = 1792)
  k_fuseA<<<NTOK / 4 + 1792, 256, 0, stream>>>(h, rwT, assign, wgt, h16, w1, img1);
  k_sort<<<1, 1024, 0, stream>>>(assign, wsI, list, wsI + 64, wsI + 48);
  // gemm1 (32*45 = 1440) || prep(w2) (14*16*8 = 1792)
  k_fuseB<<<1440 + 1792, 256, 0, stream>>>(h16, img1, b1, hid, wsI, list, w2, img2);
  k_gemm2<<<dim3(DDIM / 64, 45), 256, 0, stream>>>(hid, img2, b2, wgt, out, wsI, list);
}

// Round 15
// 166.619 us; speedup vs baseline: 1.3888x; 1.0028x over previous
//
#include <hip/hip_runtime.h>
#include <hip/hip_bf16.h>

// Problem: B=2,S=2048,D=1024,E=14,F=2048; N=4096 tokens.
// BYTE-EXACT re-submit of R11 (last passing kernel, 167 us) to re-anchor
// after three identical-absmax failures (R12/R13/R14). See journal: either
// the R12-14 diffs carry one unseen bug, or R11's schedule masks a race --
// this run distinguishes the two.
//
// ws layout (bytes), ws_size ~= 448MB:
//   [0)        ints: cnt[0..14) @0, ntl @ int48, tiles @ int64..160,
//              assign @ int160..4256, wgt(f32) @ int4256..8352
//   [65536)    list: 14 regions x 4096 ints (224KB)
//   [294912)   rwT: transposed router_w (14x1024 f32, 57KB)
//   [393216)   hid bf16 (16.78MB)
//   [17170432) h16 bf16 (8.39MB)
//   [25559040) img1 (29.36MB)  -- swizzled bf16 w1 tile images
//   [54919168) img2 (29.36MB)  -- swizzled bf16 w2 tile images
// total need: 84279296 bytes.
//
// Launch graph (5 dispatches):
//   k_init -> k_fuseA{router || prep(w1)} -> k_sort
//          -> k_fuseB{gemm1 || prep(w2)} -> k_gemm2

#define NTOK 4096
#define NEXP 14
#define DDIM 1024
#define FDIM 2048

typedef __attribute__((ext_vector_type(8))) short short8;
typedef __attribute__((ext_vector_type(4))) float floatx4;

__device__ __forceinline__ unsigned bfr(float f) {  // f32 -> bf16 bits, RNE
  unsigned u = __float_as_uint(f);
  return (u + 0x7FFFu + ((u >> 16) & 1u)) >> 16;
}
__device__ __forceinline__ unsigned pk2(float a, float b) {
  return bfr(a) | (bfr(b) << 16);
}

__device__ __forceinline__ void gload16(const void* g, void* l) {
  __builtin_amdgcn_global_load_lds((const __attribute__((address_space(1))) void*)g,
                                   (__attribute__((address_space(3))) void*)l, 16, 0, 0);
}

struct GemmSh {
  char sA[2][16384];  // bf16 [128 rows][64 k], XOR-swizzled via source
  char sB[2][8192];   // bf16 [64 cols][64 k], image bytes == swizzled layout
  int tokL[128];
  float wgtL[128];
};
union FuseSh {
  GemmSh g;
  float t32[4096];
};

// build transposed router weights rwT[e][d]
__global__ void k_init(const float* __restrict__ rw, float* __restrict__ rwT) {
  int i = blockIdx.x * 256 + threadIdx.x;
  if (i < DDIM * NEXP) rwT[(i % NEXP) * DDIM + i / NEXP] = rw[i];
}

// ---- router body: one wave per token, no LDS, no atomics ----
__device__ __forceinline__ void router_body(
    int bid, const float* __restrict__ x, const float* __restrict__ rwT,
    int* __restrict__ assign, float* __restrict__ wgt,
    unsigned short* __restrict__ h16) {
  int wid = threadIdx.x >> 6, lane = threadIdx.x & 63;
  int n = bid * 4 + wid;
  const float* xr = x + (size_t)n * DDIM;
  unsigned short* hr = h16 + (size_t)n * DDIM;
  double acc[NEXP];
#pragma unroll
  for (int e = 0; e < NEXP; e++) acc[e] = 0.0;
#pragma unroll
  for (int i = 0; i < 4; i++) {
    int d0 = i * 256 + lane * 4;
    float4 xv = *(const float4*)(xr + d0);
    uint2 hb;
    hb.x = pk2(xv.x, xv.y);
    hb.y = pk2(xv.z, xv.w);
    *(uint2*)(hr + d0) = hb;
    double x0 = xv.x, x1 = xv.y, x2 = xv.z, x3 = xv.w;
#pragma unroll
    for (int e = 0; e < NEXP; e++) {
      float4 rv = *(const float4*)(rwT + e * DDIM + d0);
      acc[e] += x0 * (double)rv.x + x1 * (double)rv.y + x2 * (double)rv.z + x3 * (double)rv.w;
    }
  }
#pragma unroll
  for (int e = 0; e < NEXP; e++)
    for (int m = 32; m > 0; m >>= 1) acc[e] += __shfl_xor(acc[e], m, 64);
  int best = 0;
  double bv = acc[0];
#pragma unroll
  for (int e = 1; e < NEXP; e++)
    if (acc[e] > bv) { bv = acc[e]; best = e; }
  float s = 0.f;
#pragma unroll
  for (int e = 0; e < NEXP; e++) s += expf((float)(acc[e] - bv));
  if (lane == 0) {
    wgt[n] = 1.0f / s;
    assign[n] = best;
  }
}

// ---- weight-image prep body: 4 k-tiles per block (z-loop) ----
// Emits exact byte image of the GEMM's swizzled LDS B-tile:
//   chunk ci = col*8 + (k8 ^ (col&7)); bytes = bf16 W[k8*8+j][col], j=0..7.
// LDS f32 transpose tile dword-swizzled: dw = k*64 + (n ^ (k&31)).
__device__ __forceinline__ void prep_body(float* __restrict__ t32,
                                          const float* __restrict__ W,
                                          unsigned short* __restrict__ img,
                                          int K, int N, int b) {
  int KB = K >> 6, NB = N >> 6, K4 = KB >> 2;
  int kb4 = b % K4;
  int nb_ = b / K4;
  int nblk = nb_ % NB, e = nb_ / NB;
  int t = threadIdx.x;
  int k = t >> 4, n4 = (t & 15) * 4;
  for (int z = 0; z < 4; z++) {
    int kblk = kb4 * 4 + z;
    const float* src = W + (size_t)e * K * N + (size_t)(kblk * 64) * N + nblk * 64;
#pragma unroll
    for (int j = 0; j < 4; j++) {
      int kk = k + j * 16;
      float4 v = *(const float4*)(src + (size_t)kk * N + n4);
      int sw = kk & 31;
      t32[kk * 64 + ((n4 + 0) ^ sw)] = v.x;
      t32[kk * 64 + ((n4 + 1) ^ sw)] = v.y;
      t32[kk * 64 + ((n4 + 2) ^ sw)] = v.z;
      t32[kk * 64 + ((n4 + 3) ^ sw)] = v.w;
    }
    __syncthreads();
    unsigned short* dst = img + (size_t)((e * NB + nblk) * KB + kblk) * 4096;
#pragma unroll
    for (int c = 0; c < 2; c++) {
      int ci = t + c * 256;
      int col = ci >> 3, q = ci & 7, k8 = q ^ (col & 7);
      float f[8];
#pragma unroll
      for (int j = 0; j < 8; j++) {
        int kk = k8 * 8 + j;
        f[j] = t32[kk * 64 + (col ^ (kk & 31))];
      }
      uint4 o;
      o.x = pk2(f[0], f[1]);
      o.y = pk2(f[2], f[3]);
      o.z = pk2(f[4], f[5]);
      o.w = pk2(f[6], f[7]);
      *(uint4*)(dst + ci * 8) = o;
    }
    __syncthreads();
  }
}

// ---- fused A: router (1024 blocks) || prep(w1) (1792 blocks) ----
__global__ __launch_bounds__(256) void k_fuseA(
    const float* __restrict__ x, const float* __restrict__ rwT,
    int* __restrict__ assign, float* __restrict__ wgt,
    unsigned short* __restrict__ h16,
    const float* __restrict__ w1, unsigned short* __restrict__ img1) {
  __shared__ float t32[4096];
  int bid = blockIdx.x;
  if (bid < NTOK / 4) {
    router_body(bid, x, rwT, assign, wgt, h16);
  } else {
    prep_body(t32, w1, img1, DDIM, FDIM, bid - NTOK / 4);
  }
}

// single block, 1024 threads: ballot-based stable counting sort, no atomics.
__global__ __launch_bounds__(1024) void k_sort(
    const int* __restrict__ assign, int* __restrict__ cnt,
    int* __restrict__ list, int* __restrict__ tiles, int* __restrict__ ntl) {
  __shared__ int clds[64][NEXP];
  __shared__ int tot[16];
  __shared__ int tstart[NEXP + 1];
  int tid = threadIdx.x;
  int wv = tid >> 6, lane = tid & 63;
  unsigned long long below = (1ull << lane) - 1ull;
  int e4[4], r4[4];
#pragma unroll
  for (int t = 0; t < 4; t++) {
    int n = wv * 256 + t * 64 + lane;
    int e = assign[n];
    int rank = 0, gcnt = 0;
#pragma unroll
    for (int xx = 0; xx < NEXP; xx++) {
      unsigned long long m = __ballot(e == xx);
      if (e == xx) rank = __popcll(m & below);
      if (lane == xx) gcnt = __popcll(m);
    }
    e4[t] = e;
    r4[t] = rank;
    if (lane < NEXP) clds[wv * 4 + t][lane] = gcnt;
  }
  __syncthreads();
  if (wv < NEXP) {
    int v = clds[lane][wv];
    int s = v;
    for (int m = 1; m < 64; m <<= 1) {
      int t = __shfl_up(s, m, 64);
      if (lane >= m) s += t;
    }
    clds[lane][wv] = s - v;
    if (lane == 63) {
      cnt[wv] = s;
      tot[wv] = s;
    }
  }
  __syncthreads();
#pragma unroll
  for (int t = 0; t < 4; t++) {
    int n = wv * 256 + t * 64 + lane;
    int e = e4[t];
    int pos = clds[wv * 4 + t][e] + r4[t];
    list[e * NTOK + pos] = n;
  }
  if (wv == 15) {
    int c = (lane < NEXP) ? tot[lane] : 0;
    int nt = (c + 127) >> 7;
    int st = nt;
    for (int m = 1; m < 64; m <<= 1) {
      int t = __shfl_up(st, m, 64);
      if (lane >= m) st += t;
    }
    if (lane < NEXP) tstart[lane] = st - nt;
    if (lane == NEXP - 1) {
      tstart[NEXP] = st;
      *ntl = st;
    }
    int totT = __shfl(st, NEXP - 1, 64);
    if (lane < totT) {
      int e = 0;
      while (tstart[e + 1] <= lane) e++;
      tiles[2 * lane] = e;
      tiles[2 * lane + 1] = (lane - tstart[e]) * 128;
    }
  }
}

// ---- image-GEMM body: tile 128x64, BK=64, 4 waves (2x2, each 64x32) ----
// BOTH operands via global_load_lds; double-buffered LDS, 2 raw barriers/iter,
// counted s_waitcnt vmcnt(6) (T4 -- never drains in the loop).
template <int LAYER>
__device__ __forceinline__ void gemm_body(
    GemmSh* sh, int tI, int n0,
    const unsigned short* __restrict__ Xb, const unsigned short* __restrict__ img,
    const float* __restrict__ Bias, const float* __restrict__ wgt,
    unsigned short* __restrict__ outB, float* __restrict__ outF,
    const int* __restrict__ wsI, const int* __restrict__ list) {
  constexpr int K = (LAYER == 1) ? DDIM : FDIM;
  constexpr int N = (LAYER == 1) ? FDIM : DDIM;
  constexpr int NIT = K / 64;
  constexpr int KB = K / 64, NB = N / 64;

  const int* cnt = wsI;
  const int* ntl = wsI + 48;
  const int* tiles = wsI + 64;

  if (tI >= *ntl) return;
  int e = tiles[2 * tI], m0 = tiles[2 * tI + 1];
  int rows = cnt[e] - m0;
  int base = e * NTOK + m0;

  char (*sA)[16384] = sh->sA;
  char (*sB)[8192] = sh->sB;
  int* tokL = sh->tokL;
  float* wgtL = sh->wgtL;

  int tid = threadIdx.x;
  if (tid < 128) {
    int tok = list[base + tid] & (NTOK - 1);  // pad slots clamp to a valid token
    tokL[tid] = tok;
    if (LAYER == 2) wgtL[tid] = wgt[tok];
  }
  __syncthreads();

  int lane = tid & 63, wid = tid >> 6, wm = wid >> 1, wn = wid & 1;

  // A source: per-lane pre-swizzled; dest = wave-uniform chunk base (+lane*16 HW)
  const char* gA[4];
  {
    unsigned sw = (unsigned)(((lane & 7) * 16) ^ ((lane >> 3) << 4));
#pragma unroll
    for (int j = 0; j < 4; j++) {
      int row = wid * 32 + j * 8 + (lane >> 3);
      gA[j] = (const char*)(Xb + (size_t)tokL[row] * K) + sw;
    }
  }
  // B source: linear per-lane walk through this (e, n-block)'s image tiles
  const char* gB = (const char*)img +
                   (size_t)((e * NB + (n0 >> 6)) * KB) * 8192 + wid * 2048 + lane * 16;

  floatx4 acc[4][2];
#pragma unroll
  for (int i = 0; i < 4; i++)
#pragma unroll
    for (int j = 0; j < 2; j++) acc[i][j] = (floatx4){0.f, 0.f, 0.f, 0.f};

#define GLOAD_AB(it, p)                                                     \
  do {                                                                      \
    _Pragma("unroll") for (int j = 0; j < 4; j++)                           \
        gload16(gA[j] + (size_t)(it) * 128, sA[p] + (wid * 4 + j) * 1024);  \
    _Pragma("unroll") for (int j = 0; j < 2; j++)                           \
        gload16(gB + (size_t)(it) * 8192 + j * 1024,                        \
                sB[p] + wid * 2048 + j * 1024);                             \
  } while (0)

#define MFMA_PHASE(P)                                                                    \
  do {                                                                                   \
    const char* A_ = sA[P];                                                              \
    const char* B_ = sB[P];                                                              \
    _Pragma("unroll") for (int kc = 0; kc < 2; kc++) {                                   \
      short8 af[4], bf[2];                                                               \
      int kb = kc * 64 + ((lane >> 4) << 4);                                             \
      _Pragma("unroll") for (int f = 0; f < 4; f++) {                                    \
        int rr = wm * 64 + f * 16 + (lane & 15);                                         \
        af[f] = *(const short8*)(A_ + rr * 128 + (kb ^ ((rr & 7) << 4)));                \
      }                                                                                  \
      _Pragma("unroll") for (int f = 0; f < 2; f++) {                                    \
        int cc = wn * 32 + f * 16 + (lane & 15);                                         \
        bf[f] = *(const short8*)(B_ + cc * 128 + (kb ^ ((cc & 7) << 4)));                \
      }                                                                                  \
      _Pragma("unroll") for (int fm = 0; fm < 4; fm++)                                   \
      _Pragma("unroll") for (int fn = 0; fn < 2; fn++)                                   \
          acc[fm][fn] =                                                                  \
              __builtin_amdgcn_mfma_f32_16x16x32_bf16(af[fm], bf[fn], acc[fm][fn], 0, 0, 0); \
    }                                                                                    \
  } while (0)

  GLOAD_AB(0, 0);
  for (int it = 0; it < NIT - 1; ++it) {
    int p = it & 1;
    __builtin_amdgcn_sched_barrier(0);
    __builtin_amdgcn_s_barrier();  // all reads of buf p^1 (iter it-1) done
    GLOAD_AB(it + 1, p ^ 1);
    __builtin_amdgcn_sched_barrier(0);
    asm volatile("s_waitcnt vmcnt(6)" ::: "memory");  // iter-it loads landed
    __builtin_amdgcn_s_barrier();
    __builtin_amdgcn_sched_barrier(0);
    MFMA_PHASE(p);
  }
  {
    int p = (NIT - 1) & 1;
    __builtin_amdgcn_sched_barrier(0);
    __builtin_amdgcn_s_barrier();
    asm volatile("s_waitcnt vmcnt(0)" ::: "memory");
    __builtin_amdgcn_s_barrier();
    __builtin_amdgcn_sched_barrier(0);
    MFMA_PHASE(p);
  }
#undef GLOAD_AB
#undef MFMA_PHASE

  // epilogue. C frag mapping: col = lane&15, row = (lane>>4)*4 + r
  float bv[2];
#pragma unroll
  for (int f = 0; f < 2; f++) bv[f] = Bias[(size_t)e * N + n0 + wn * 32 + f * 16 + (lane & 15)];
#pragma unroll
  for (int fm = 0; fm < 4; fm++) {
#pragma unroll
    for (int r = 0; r < 4; r++) {
      int gr = wm * 64 + fm * 16 + ((lane >> 4) << 2) + r;
      if (gr < rows) {
        int tok = tokL[gr];
#pragma unroll
        for (int fn = 0; fn < 2; fn++) {
          int col = n0 + wn * 32 + fn * 16 + (lane & 15);
          float v = acc[fm][fn][r] + bv[fn];
          if (LAYER == 1) {
            v = 0.5f * v * (1.0f + erff(v * 0.70710678118654752f));  // exact GELU
            outB[(size_t)tok * FDIM + col] = (unsigned short)bfr(v);
          } else {
            outF[(size_t)tok * DDIM + col] = v * wgtL[gr];
          }
        }
      }
    }
  }
}

// ---- fused B: gemm1 (1440 blocks, flat id keeps x32 -> same-XCD) || prep(w2) ----
__global__ __launch_bounds__(256, 3) void k_fuseB(
    const unsigned short* __restrict__ h16, const unsigned short* __restrict__ img1,
    const float* __restrict__ b1, unsigned short* __restrict__ hid,
    const int* __restrict__ wsI, const int* __restrict__ list,
    const float* __restrict__ w2, unsigned short* __restrict__ img2) {
  __shared__ FuseSh sh;
  int bid = blockIdx.x;
  if (bid < (FDIM / 64) * 45) {
    gemm_body<1>(&sh.g, bid >> 5, (bid & 31) << 6, h16, img1, b1, nullptr, hid,
                 nullptr, wsI, list);
  } else {
    prep_body(sh.t32, w2, img2, FDIM, DDIM, bid - (FDIM / 64) * 45);
  }
}

__global__ __launch_bounds__(256, 3) void k_gemm2(
    const unsigned short* __restrict__ hid, const unsigned short* __restrict__ img2,
    const float* __restrict__ b2, const float* __restrict__ wgt,
    float* __restrict__ outF, const int* __restrict__ wsI,
    const int* __restrict__ list) {
  __shared__ GemmSh sh;
  gemm_body<2>(&sh, blockIdx.y, blockIdx.x << 6, hid, img2, b2, wgt, nullptr,
               outF, wsI, list);
}

extern "C" void kernel_launch(void* const* d_in, const int* in_sizes, int n_in,
                              void* d_out, int out_size, void* d_ws, size_t ws_size,
                              hipStream_t stream) {
  const float* h  = (const float*)d_in[0];
  const float* rw = (const float*)d_in[1];
  const float* w1 = (const float*)d_in[2];
  const float* b1 = (const float*)d_in[3];
  const float* w2 = (const float*)d_in[4];
  const float* b2 = (const float*)d_in[5];
  float* out = (float*)d_out;

  int* wsI = (int*)d_ws;
  int* assign = wsI + 160;
  float* wgt = (float*)(wsI + 4256);
  int* list = (int*)((char*)d_ws + 65536);                           // 14 x 4096 ints
  float* rwT = (float*)((char*)d_ws + 294912);                       // 57KB
  unsigned short* hid  = (unsigned short*)((char*)d_ws + 393216);    // 16.78MB
  unsigned short* h16  = (unsigned short*)((char*)d_ws + 17170432);  // 8.39MB
  unsigned short* img1 = (unsigned short*)((char*)d_ws + 25559040);  // 29.36MB
  unsigned short* img2 = (unsigned short*)((char*)d_ws + 54919168);  // 29.36MB

  k_init<<<56, 256, 0, stream>>>(rw, rwT);
  // router (1024) || prep(w1) (14*32*4 = 1792)
  k_fuseA<<<NTOK / 4 + 1792, 256, 0, stream>>>(h, rwT, assign, wgt, h16, w1, img1);
  k_sort<<<1, 1024, 0, stream>>>(assign, wsI, list, wsI + 64, wsI + 48);
  // gemm1 (32*45 = 1440) || prep(w2) (14*16*8 = 1792)
  k_fuseB<<<1440 + 1792, 256, 0, stream>>>(h16, img1, b1, hid, wsI, list, w2, img2);
  k_gemm2<<<dim3(DDIM / 64, 45), 256, 0, stream>>>(hid, img2, b2, wgt, out, wsI, list);
}